// Round 4
// baseline (338.915 us; speedup 1.0000x reference)
//
#include <hip/hip_runtime.h>

#define TB 2
#define TT 2048
#define TDIM 2048
#define NHEADS 16
#define KVHEADS 4
#define HD 128

typedef unsigned short u16;
typedef unsigned int u32;
typedef __attribute__((ext_vector_type(8))) short short8;
typedef __attribute__((ext_vector_type(4))) float float4_t;

__device__ __forceinline__ float b2f(u16 u) {
    union { u32 i; float f; } v; v.i = ((u32)u) << 16; return v.f;
}
__device__ __forceinline__ u16 f2b(float f) {
    union { float f; u32 i; } v; v.f = f;
    u32 r = (v.i + 0x7FFFu + ((v.i >> 16) & 1u)) >> 16;
    return (u16)r;
}
__device__ __forceinline__ u32 fbits(float f) {
    union { float f; u32 i; } v; v.f = f; return v.i;
}

// async global->LDS, 16B/lane; LDS dest must be wave-uniform base (+lane*16)
__device__ __forceinline__ void gl_lds16(const void* g, void* l) {
    __builtin_amdgcn_global_load_lds((const __attribute__((address_space(1))) void*)g,
                                     (__attribute__((address_space(3))) void*)l, 16, 0, 0);
}

// ---------------------------------------------------------------------------
// bf16 GEMM: C[M,N] = A[M,K] * B[K,N], B pre-transposed (BT is N x K, bf16).
// 128x128 tile, BK=64, 4 waves (2x2), m97 structure. Optional fused RoPE.
// NOTE: 256^2 8-phase template was tried (R1): per-active-CU parity with this
// kernel (686 vs 718 TF) but N=3072 gives only 192 blocks < 256 CUs -> -25%.
// This shape structurally favors the 768-block 128^2 layout (3 blocks/CU).
// ---------------------------------------------------------------------------
template <bool F32OUT, bool ROPE>
__global__ __launch_bounds__(256, 3)
void gemm_bt(const u16* __restrict__ A, const u16* __restrict__ BT,
             void* __restrict__ Cv, int M, int N, int K,
             const float* __restrict__ fc, const float* __restrict__ fs) {
    __shared__ __align__(16) u16 As[128 * 64];
    __shared__ __align__(16) u16 Bs[128 * 64];
    const int tid  = threadIdx.x;
    const int wave = tid >> 6, lane = tid & 63;
    const int quad = lane >> 4, l16 = lane & 15;
    const int wm = wave >> 1, wn = wave & 1;
    const int row0 = blockIdx.y * 128, col0 = blockIdx.x * 128;

    float4_t acc[4][4];
#pragma unroll
    for (int i = 0; i < 4; i++)
#pragma unroll
        for (int j = 0; j < 4; j++) acc[i][j] = (float4_t){0.f, 0.f, 0.f, 0.f};

    for (int kk = 0; kk < K; kk += 64) {
        __syncthreads();
#pragma unroll
        for (int i = 0; i < 4; i++) {
            int n = i * 256 + wave * 64 + lane;
            int r = n >> 3, c = (n & 7) ^ (r & 7);
            gl_lds16(A  + (size_t)(row0 + r) * K + kk + c * 8, &As[(i * 256 + wave * 64) * 8]);
            gl_lds16(BT + (size_t)(col0 + r) * K + kk + c * 8, &Bs[(i * 256 + wave * 64) * 8]);
        }
        __syncthreads();
#pragma unroll
        for (int ks = 0; ks < 2; ks++) {
            short8 af[4], bf[4];
#pragma unroll
            for (int mt = 0; mt < 4; mt++) {
                int m = wm * 64 + mt * 16 + l16;
                af[mt] = *(const short8*)&As[(m * 8 + ((ks * 4 + quad) ^ (l16 & 7))) * 8];
            }
#pragma unroll
            for (int nt = 0; nt < 4; nt++) {
                int n = wn * 64 + nt * 16 + l16;
                bf[nt] = *(const short8*)&Bs[(n * 8 + ((ks * 4 + quad) ^ (l16 & 7))) * 8];
            }
#pragma unroll
            for (int mt = 0; mt < 4; mt++)
#pragma unroll
                for (int nt = 0; nt < 4; nt++)
                    acc[mt][nt] = __builtin_amdgcn_mfma_f32_16x16x32_bf16(
                        af[mt], bf[nt], acc[mt][nt], 0, 0, 0);
        }
    }
    // epilogue: C/D layout col=lane&15, row=quad*4+reg  [m89/m91]
    const bool do_rope = ROPE && (col0 < 2560);
#pragma unroll
    for (int mt = 0; mt < 4; mt++)
#pragma unroll
        for (int nt = 0; nt < 4; nt++)
#pragma unroll
            for (int r = 0; r < 4; r++) {
                int row = row0 + wm * 64 + mt * 16 + quad * 4 + r;
                int col = col0 + wn * 64 + nt * 16 + l16;
                float v = acc[mt][nt][r];
                if (ROPE && do_rope) {
                    float other = __shfl_xor(v, 1, 64);
                    int t = row & (TT - 1);
                    int i0 = (col & (HD - 1)) >> 1;
                    float c = fc[t * 64 + i0], s = fs[t * 64 + i0];
                    v = (col & 1) ? fmaf(v, c, other * s) : fmaf(v, c, -other * s);
                }
                if (F32OUT)
                    ((float*)Cv)[(size_t)row * N + col] = v;
                else
                    ((u16*)Cv)[(size_t)row * N + col] = f2b(v);
            }
}

// ---------------------------------------------------------------------------
// Fused prep: x fp32->bf16 (blocks 0..8191) + all four weight transposes
// (fp32 KxN -> bf16 NxK, blocks 8192..18431). One launch instead of two.
// ---------------------------------------------------------------------------
__global__ void prep(const float* __restrict__ x, u16* __restrict__ xb,
                     const float* __restrict__ wq, const float* __restrict__ wk,
                     const float* __restrict__ wv, const float* __restrict__ wo,
                     u16* __restrict__ WT, u16* __restrict__ woT) {
    const int bid = blockIdx.x;
    if (bid < 8192) {
        size_t i = ((size_t)bid * 256 + threadIdx.x) * 4;
        float4 v = *(const float4*)(x + i);
        ushort4 o;
        o.x = f2b(v.x); o.y = f2b(v.y); o.z = f2b(v.z); o.w = f2b(v.w);
        *(ushort4*)(xb + i) = o;
        return;
    }
    const int rem = bid - 8192;
    const int bx = rem % 160;      // 160 col-tiles as in cvt_transpose4
    const int by = rem / 160;      // 64 row-tiles
    const float* in; u16* out; int cols, cx;
    if (bx < 64)      { in = wq; out = WT;                         cols = 2048; cx = bx; }
    else if (bx < 80) { in = wk; out = WT + (size_t)2048 * 2048;   cols = 512;  cx = bx - 64; }
    else if (bx < 96) { in = wv; out = WT + (size_t)2560 * 2048;   cols = 512;  cx = bx - 80; }
    else              { in = wo; out = woT;                        cols = 2048; cx = bx - 96; }
    const int rows = 2048;
    __shared__ u16 tile[32][33];
    int c0 = cx * 32, r0 = by * 32;
    int tx = threadIdx.x & 31, ty = threadIdx.x >> 5;
#pragma unroll
    for (int i = 0; i < 4; i++)
        tile[ty + i * 8][tx] = f2b(in[(size_t)(r0 + ty + i * 8) * cols + c0 + tx]);
    __syncthreads();
#pragma unroll
    for (int i = 0; i < 4; i++)
        out[(size_t)(c0 + ty + i * 8) * rows + r0 + tx] = tile[tx][ty + i * 8];
}

// V slice of QKV (bf16, cols 2560 + kv*128) -> Vt[b][kv][d][t] (bf16)
__global__ void transpose_v(const u16* __restrict__ QKV, u16* __restrict__ Vt) {
    int z = blockIdx.z, b = z >> 2, kv = z & 3;
    const u16* in = QKV + (size_t)b * TT * 3072 + 2560 + kv * HD;  // (t,d)
    u16* out = Vt + (size_t)z * HD * TT;                           // (d,t)
    __shared__ u16 tile[32][33];
    int t0 = blockIdx.x * 32, d0 = blockIdx.y * 32;
    int tx = threadIdx.x & 31, ty = threadIdx.x >> 5;
#pragma unroll
    for (int i = 0; i < 4; i++)
        tile[ty + i * 8][tx] = in[(size_t)(t0 + ty + i * 8) * 3072 + d0 + tx];
    __syncthreads();
#pragma unroll
    for (int i = 0; i < 4; i++)
        out[(size_t)(d0 + ty + i * 8) * TT + t0 + tx] = tile[tx][ty + i * 8];
}

// ---------------------------------------------------------------------------
// Causal flash attention v8: CONCURRENCY fix. R3 showed occupancy pinned at
// 20% because grid (512) == residency slots (512 @ 2 blocks/CU). v8:
//  (a) single-buffer K: stageK(kt+1) is issued after B2, by which point all
//      waves' QK^T reads of Ks completed -- the dbuf bought zero overlap.
//      LDS 58368 -> 41984 B -> 3 blocks/CU (12 waves).
//  (b) grid (32,32) = 1024 one-q-tile blocks > 768 slots -> backfill absorbs
//      the causal imbalance; long tiles first (qb = 31-x) for a short tail.
// Keeps: async V stage under softmax, setprio (T5), defer-max (T13).
// ---------------------------------------------------------------------------
#define PSTR 72
__global__ __launch_bounds__(256, 3)
void attn(const u16* __restrict__ QKV, const u16* __restrict__ Vt,
          u16* __restrict__ O) {
    const int qb = 31 - blockIdx.x;  // q-tile, longest first
    const int y  = blockIdx.y;       // (b, head): b = y>>4, h = y&15
    const int b  = y >> 4;
    const int h  = y & 15;
    const int kvh = h >> 2;
    const int tid = threadIdx.x, w = tid >> 6, lane = tid & 63;
    const int quad = lane >> 4, l16 = lane & 15;

    __shared__ __align__(16) u16 Ks[64 * 128];      // [key][16 chunks] sw: c^(key&15)
    __shared__ __align__(16) u16 Vs[128 * 64];      // [d][8 chunks]    sw: c^(d&7)
    __shared__ __align__(16) u16 Ps[4][16 * PSTR];  // per-wave strip

    const u16* Kbase = QKV + (size_t)b * TT * 3072 + 2048 + kvh * HD;
    const u16* Vbase = Vt + (size_t)(b * 4 + kvh) * HD * TT;
    const float Cl = 0.12753102474f;  // (1/sqrt(128)) * log2(e)

    auto stageK = [&](int kt) {
#pragma unroll
        for (int i = 0; i < 4; i++) {
            int n = i * 256 + w * 64 + lane;
            int r = n >> 4, c = (n & 15) ^ (r & 15);
            gl_lds16(Kbase + (size_t)(kt * 64 + r) * 3072 + c * 8,
                     &Ks[(i * 256 + w * 64) * 8]);
        }
    };
    auto stageV = [&](int kt) {
#pragma unroll
        for (int i = 0; i < 4; i++) {
            int n = i * 256 + w * 64 + lane;
            int d = n >> 3, c = (n & 7) ^ (d & 7);
            gl_lds16(Vbase + (size_t)d * TT + kt * 64 + c * 8,
                     &Vs[(i * 256 + w * 64) * 8]);
        }
    };

    stageK(0);

    // Q fragments to registers (B-layout: l16 = q-row)
    short8 qf[4];
    {
        const u16* Qrow = QKV + ((size_t)b * TT + qb * 64 + w * 16 + l16) * 3072
                          + h * HD;
#pragma unroll
        for (int ks = 0; ks < 4; ks++)
            qf[ks] = *(const short8*)(Qrow + ks * 32 + quad * 8);
    }

    float4_t o[8];
#pragma unroll
    for (int i = 0; i < 8; i++) o[i] = (float4_t){0.f, 0.f, 0.f, 0.f};
    float mi = -1e30f, li = 0.f;
    const int qg = qb * 64 + w * 16 + l16;  // this lane's q-row (S^T col)

    for (int kt = 0; kt <= qb; kt++) {
        __syncthreads();        // B1: K[kt] landed; prev PV done reading Vs
        stageV(kt);             // async; lands under S^T + softmax

        // S^T = K·Q^T
        float4_t st[4];
#pragma unroll
        for (int nt = 0; nt < 4; nt++) st[nt] = (float4_t){0.f, 0.f, 0.f, 0.f};
#pragma unroll
        for (int ks = 0; ks < 4; ks++) {
            short8 af[4];
#pragma unroll
            for (int nt = 0; nt < 4; nt++)
                af[nt] = *(const short8*)&Ks[((nt * 16 + l16) * 16 +
                                             ((ks * 4 + quad) ^ l16)) * 8];
            __builtin_amdgcn_s_setprio(1);
#pragma unroll
            for (int nt = 0; nt < 4; nt++)
                st[nt] = __builtin_amdgcn_mfma_f32_16x16x32_bf16(
                    af[nt], qf[ks], st[nt], 0, 0, 0);
            __builtin_amdgcn_s_setprio(0);
        }

        // mask + softmax + pack
        if (kt == qb) {
#pragma unroll
            for (int nt = 0; nt < 4; nt++)
#pragma unroll
                for (int r = 0; r < 4; r++) {
                    int key = kt * 64 + nt * 16 + quad * 4 + r;
                    if (key > qg) st[nt][r] = -3e38f;
                }
        }
        float pm = -3e38f;
#pragma unroll
        for (int nt = 0; nt < 4; nt++)
#pragma unroll
            for (int r = 0; r < 4; r++) pm = fmaxf(pm, st[nt][r]);
        pm = fmaxf(pm, __shfl_xor(pm, 16, 64));
        pm = fmaxf(pm, __shfl_xor(pm, 32, 64));
        // T13 defer-max: threshold 62.7 raw = 8 in log2 -> P <= 2^8
        const bool need = !__all(pm - mi <= 62.7f);
        float alpha_v = 1.f;
        if (need) {
            float mnew = fmaxf(mi, pm);
            alpha_v = __builtin_amdgcn_exp2f((mi - mnew) * Cl);
            mi = mnew;
        }
        const float mC = mi * Cl;
        float rs = 0.f;
#pragma unroll
        for (int nt = 0; nt < 4; nt++)
#pragma unroll
            for (int r = 0; r < 4; r++) {
                float e = __builtin_amdgcn_exp2f(fmaf(st[nt][r], Cl, -mC));
                st[nt][r] = e;
                rs += e;
            }
        rs += __shfl_xor(rs, 16, 64);
        rs += __shfl_xor(rs, 32, 64);
        li = li * alpha_v + rs;

        // P -> strip (truncation-pack via v_perm, b64 writes)
#pragma unroll
        for (int nt = 0; nt < 4; nt++) {
            uint2 pk;
            pk.x = __builtin_amdgcn_perm(fbits(st[nt][1]), fbits(st[nt][0]), 0x07060302u);
            pk.y = __builtin_amdgcn_perm(fbits(st[nt][3]), fbits(st[nt][2]), 0x07060302u);
            *(uint2*)&Ps[w][l16 * PSTR + nt * 16 + quad * 4] = pk;
        }
        // rescale O only when the running max moved (o rows are q=quad*4+r)
        if (need) {
            float a_o[4];
#pragma unroll
            for (int r = 0; r < 4; r++) a_o[r] = __shfl(alpha_v, quad * 4 + r, 64);
#pragma unroll
            for (int n2 = 0; n2 < 8; n2++)
#pragma unroll
                for (int r = 0; r < 4; r++) o[n2][r] *= a_o[r];
        }

        __syncthreads();                 // B2: V[kt] landed; all Ks reads done
        if (kt < qb) stageK(kt + 1);     // overwrite Ks; lands at next B1

        // O += P·V
#pragma unroll
        for (int ks2 = 0; ks2 < 2; ks2++) {
            short8 ap = *(const short8*)&Ps[w][l16 * PSTR + ks2 * 32 + quad * 8];
            __builtin_amdgcn_s_setprio(1);
#pragma unroll
            for (int n2 = 0; n2 < 8; n2++) {
                short8 bv = *(const short8*)&Vs[((n2 * 16 + l16) * 8 +
                                                ((ks2 * 4 + quad) ^ (l16 & 7))) * 8];
                o[n2] = __builtin_amdgcn_mfma_f32_16x16x32_bf16(ap, bv, o[n2], 0, 0, 0);
            }
            __builtin_amdgcn_s_setprio(0);
        }
    }

    // epilogue
    float linv[4];
#pragma unroll
    for (int r = 0; r < 4; r++) linv[r] = 1.0f / __shfl(li, quad * 4 + r, 64);
    u16* Ob2 = O + ((size_t)b * TT + qb * 64 + w * 16) * TDIM + h * HD;
#pragma unroll
    for (int n2 = 0; n2 < 8; n2++)
#pragma unroll
        for (int r = 0; r < 4; r++)
            Ob2[(size_t)(quad * 4 + r) * TDIM + n2 * 16 + l16] =
                f2b(o[n2][r] * linv[r]);
}

// ---------------------------------------------------------------------------
extern "C" void kernel_launch(void* const* d_in, const int* in_sizes, int n_in,
                              void* d_out, int out_size, void* d_ws, size_t ws_size,
                              hipStream_t stream) {
    const float* x  = (const float*)d_in[0];
    const float* fc = (const float*)d_in[1];
    const float* fs = (const float*)d_in[2];
    const float* wq = (const float*)d_in[3];
    const float* wk = (const float*)d_in[4];
    const float* wv = (const float*)d_in[5];
    const float* wo = (const float*)d_in[6];
    float* out = (float*)d_out;

    char* ws = (char*)d_ws;
    size_t off = 0;
    auto alloc = [&](size_t bytes) -> void* {
        void* p = ws + off;
        off += (bytes + 255) & ~(size_t)255;
        return p;
    };
    u16* xb  = (u16*)alloc((size_t)4096 * 2048 * 2);  // x in bf16
    u16* WT  = (u16*)alloc((size_t)3072 * 2048 * 2);  // [wqT|wkT|wvT] N x K bf16
    u16* woT = (u16*)alloc((size_t)2048 * 2048 * 2);
    u16* QKV = (u16*)alloc((size_t)4096 * 3072 * 2);  // [Q|K|V] fused bf16 (roped)
    u16* Vtb = (u16*)alloc((size_t)4096 * 512 * 2);   // V^T per (b,kv): [d][t]
    u16* Ob  = (u16*)alloc((size_t)4096 * 2048 * 2);  // attention output bf16

    dim3 blk(256);
    // fused x-convert + all weight transposes (one launch)
    prep<<<dim3(8192 + 160 * 64), blk, 0, stream>>>(x, xb, wq, wk, wv, wo, WT, woT);
    // fused QKV projection with RoPE applied in the epilogue (Q|K cols only)
    gemm_bt<false, true><<<dim3(24, 32), blk, 0, stream>>>(
        xb, WT, QKV, 4096, 3072, 2048, fc, fs);
    transpose_v<<<dim3(64, 4, 8), blk, 0, stream>>>(QKV, Vtb);
    // 1024 one-q-tile blocks (> 768 residency slots -> backfill), 3 blocks/CU
    attn<<<dim3(32, 32), blk, 0, stream>>>(QKV, Vtb, Ob);
    gemm_bt<true, false><<<dim3(16, 32), blk, 0, stream>>>(
        Ob, woT, out, 4096, 2048, 2048, nullptr, nullptr);
}

// Round 5
// 299.453 us; speedup vs baseline: 1.1318x; 1.1318x over previous
//
#include <hip/hip_runtime.h>

#define TB 2
#define TT 2048
#define TDIM 2048
#define NHEADS 16
#define KVHEADS 4
#define HD 128

typedef unsigned short u16;
typedef unsigned int u32;
typedef __attribute__((ext_vector_type(8))) short short8;
typedef __attribute__((ext_vector_type(4))) float float4_t;

__device__ __forceinline__ float b2f(u16 u) {
    union { u32 i; float f; } v; v.i = ((u32)u) << 16; return v.f;
}
__device__ __forceinline__ u16 f2b(float f) {
    union { float f; u32 i; } v; v.f = f;
    u32 r = (v.i + 0x7FFFu + ((v.i >> 16) & 1u)) >> 16;
    return (u16)r;
}
__device__ __forceinline__ u32 fbits(float f) {
    union { float f; u32 i; } v; v.f = f; return v.i;
}

// async global->LDS, 16B/lane; LDS dest must be wave-uniform base (+lane*16)
__device__ __forceinline__ void gl_lds16(const void* g, void* l) {
    __builtin_amdgcn_global_load_lds((const __attribute__((address_space(1))) void*)g,
                                     (__attribute__((address_space(3))) void*)l, 16, 0, 0);
}

// ---------------------------------------------------------------------------
// bf16 GEMM: C[M,N] = A[M,K] * B[K,N], B pre-transposed (BT is N x K, bf16).
// 128x128 tile, BK=64, 4 waves (2x2), m97 structure. Optional fused RoPE.
// NOTE: 256^2 8-phase template was tried (R1): per-active-CU parity with this
// kernel (686 vs 718 TF) but N=3072 gives only 192 blocks < 256 CUs -> -25%.
// This shape structurally favors the 768-block 128^2 layout (3 blocks/CU).
// ---------------------------------------------------------------------------
template <bool F32OUT, bool ROPE>
__global__ __launch_bounds__(256, 3)
void gemm_bt(const u16* __restrict__ A, const u16* __restrict__ BT,
             void* __restrict__ Cv, int M, int N, int K,
             const float* __restrict__ fc, const float* __restrict__ fs) {
    __shared__ __align__(16) u16 As[128 * 64];
    __shared__ __align__(16) u16 Bs[128 * 64];
    const int tid  = threadIdx.x;
    const int wave = tid >> 6, lane = tid & 63;
    const int quad = lane >> 4, l16 = lane & 15;
    const int wm = wave >> 1, wn = wave & 1;
    const int row0 = blockIdx.y * 128, col0 = blockIdx.x * 128;

    float4_t acc[4][4];
#pragma unroll
    for (int i = 0; i < 4; i++)
#pragma unroll
        for (int j = 0; j < 4; j++) acc[i][j] = (float4_t){0.f, 0.f, 0.f, 0.f};

    for (int kk = 0; kk < K; kk += 64) {
        __syncthreads();
#pragma unroll
        for (int i = 0; i < 4; i++) {
            int n = i * 256 + wave * 64 + lane;
            int r = n >> 3, c = (n & 7) ^ (r & 7);
            gl_lds16(A  + (size_t)(row0 + r) * K + kk + c * 8, &As[(i * 256 + wave * 64) * 8]);
            gl_lds16(BT + (size_t)(col0 + r) * K + kk + c * 8, &Bs[(i * 256 + wave * 64) * 8]);
        }
        __syncthreads();
#pragma unroll
        for (int ks = 0; ks < 2; ks++) {
            short8 af[4], bf[4];
#pragma unroll
            for (int mt = 0; mt < 4; mt++) {
                int m = wm * 64 + mt * 16 + l16;
                af[mt] = *(const short8*)&As[(m * 8 + ((ks * 4 + quad) ^ (l16 & 7))) * 8];
            }
#pragma unroll
            for (int nt = 0; nt < 4; nt++) {
                int n = wn * 64 + nt * 16 + l16;
                bf[nt] = *(const short8*)&Bs[(n * 8 + ((ks * 4 + quad) ^ (l16 & 7))) * 8];
            }
#pragma unroll
            for (int mt = 0; mt < 4; mt++)
#pragma unroll
                for (int nt = 0; nt < 4; nt++)
                    acc[mt][nt] = __builtin_amdgcn_mfma_f32_16x16x32_bf16(
                        af[mt], bf[nt], acc[mt][nt], 0, 0, 0);
        }
    }
    // epilogue: C/D layout col=lane&15, row=quad*4+reg  [m89/m91]
    const bool do_rope = ROPE && (col0 < 2560);
#pragma unroll
    for (int mt = 0; mt < 4; mt++)
#pragma unroll
        for (int nt = 0; nt < 4; nt++)
#pragma unroll
            for (int r = 0; r < 4; r++) {
                int row = row0 + wm * 64 + mt * 16 + quad * 4 + r;
                int col = col0 + wn * 64 + nt * 16 + l16;
                float v = acc[mt][nt][r];
                if (ROPE && do_rope) {
                    float other = __shfl_xor(v, 1, 64);
                    int t = row & (TT - 1);
                    int i0 = (col & (HD - 1)) >> 1;
                    float c = fc[t * 64 + i0], s = fs[t * 64 + i0];
                    v = (col & 1) ? fmaf(v, c, other * s) : fmaf(v, c, -other * s);
                }
                if (F32OUT)
                    ((float*)Cv)[(size_t)row * N + col] = v;
                else
                    ((u16*)Cv)[(size_t)row * N + col] = f2b(v);
            }
}

// ---------------------------------------------------------------------------
// Fused prep: x fp32->bf16 (blocks 0..8191) + all four weight transposes
// (fp32 KxN -> bf16 NxK, blocks 8192..18431). One launch instead of two.
// ---------------------------------------------------------------------------
__global__ void prep(const float* __restrict__ x, u16* __restrict__ xb,
                     const float* __restrict__ wq, const float* __restrict__ wk,
                     const float* __restrict__ wv, const float* __restrict__ wo,
                     u16* __restrict__ WT, u16* __restrict__ woT) {
    const int bid = blockIdx.x;
    if (bid < 8192) {
        size_t i = ((size_t)bid * 256 + threadIdx.x) * 4;
        float4 v = *(const float4*)(x + i);
        ushort4 o;
        o.x = f2b(v.x); o.y = f2b(v.y); o.z = f2b(v.z); o.w = f2b(v.w);
        *(ushort4*)(xb + i) = o;
        return;
    }
    const int rem = bid - 8192;
    const int bx = rem % 160;      // 160 col-tiles as in cvt_transpose4
    const int by = rem / 160;      // 64 row-tiles
    const float* in; u16* out; int cols, cx;
    if (bx < 64)      { in = wq; out = WT;                         cols = 2048; cx = bx; }
    else if (bx < 80) { in = wk; out = WT + (size_t)2048 * 2048;   cols = 512;  cx = bx - 64; }
    else if (bx < 96) { in = wv; out = WT + (size_t)2560 * 2048;   cols = 512;  cx = bx - 80; }
    else              { in = wo; out = woT;                        cols = 2048; cx = bx - 96; }
    const int rows = 2048;
    __shared__ u16 tile[32][33];
    int c0 = cx * 32, r0 = by * 32;
    int tx = threadIdx.x & 31, ty = threadIdx.x >> 5;
#pragma unroll
    for (int i = 0; i < 4; i++)
        tile[ty + i * 8][tx] = f2b(in[(size_t)(r0 + ty + i * 8) * cols + c0 + tx]);
    __syncthreads();
#pragma unroll
    for (int i = 0; i < 4; i++)
        out[(size_t)(c0 + ty + i * 8) * rows + r0 + tx] = tile[tx][ty + i * 8];
}

// V slice of QKV (bf16, cols 2560 + kv*128) -> Vt[b][kv][d][t] (bf16)
__global__ void transpose_v(const u16* __restrict__ QKV, u16* __restrict__ Vt) {
    int z = blockIdx.z, b = z >> 2, kv = z & 3;
    const u16* in = QKV + (size_t)b * TT * 3072 + 2560 + kv * HD;  // (t,d)
    u16* out = Vt + (size_t)z * HD * TT;                           // (d,t)
    __shared__ u16 tile[32][33];
    int t0 = blockIdx.x * 32, d0 = blockIdx.y * 32;
    int tx = threadIdx.x & 31, ty = threadIdx.x >> 5;
#pragma unroll
    for (int i = 0; i < 4; i++)
        tile[ty + i * 8][tx] = in[(size_t)(t0 + ty + i * 8) * 3072 + d0 + tx];
    __syncthreads();
#pragma unroll
    for (int i = 0; i < 4; i++)
        out[(size_t)(d0 + ty + i * 8) * TT + t0 + tx] = tile[tx][ty + i * 8];
}

// ---------------------------------------------------------------------------
// Causal flash attention v9: GLOBAL longest-first dispatch (LPT schedule).
// R4's regression was a drain tail: qb = 31 - blockIdx.x with x fastest meant
// every y-slice re-issued long blocks; block (y=31,qb=31) was dispatched at
// position 992/1024 and ran ~alone at the end (occ 12.5%, all utils ~1/2 of
// R3). v9 linearizes the grid 1D: bid>>5 = q-selector (descending length),
// bid&31 = (b,head) -> dispatch order is globally monotone by block length;
// every backfill block is shorter than everything running; stragglers are
// 1-2 iters. Bonus: same-(b,kvh) blocks sit 32 apart -> same XCD under
// round-robin (32%8==0) -> K/V L2 locality.
// Structure per block identical to R4: single-buffer K (stageK(kt+1) after
// B2 -- all Ks reads complete before B2, dbuf bought nothing), async V stage
// under S^T+softmax, setprio (T5), defer-max (T13). LDS 41984 B, 3 blk/CU.
// ---------------------------------------------------------------------------
#define PSTR 72
__global__ __launch_bounds__(256, 3)
void attn(const u16* __restrict__ QKV, const u16* __restrict__ Vt,
          u16* __restrict__ O) {
    const int bid = blockIdx.x;      // 0..1023, 1D
    const int qb  = 31 - (bid >> 5); // q-tile, globally longest first
    const int y   = bid & 31;        // (b, head): b = y>>4, h = y&15
    const int b   = y >> 4;
    const int h   = y & 15;
    const int kvh = h >> 2;
    const int tid = threadIdx.x, w = tid >> 6, lane = tid & 63;
    const int quad = lane >> 4, l16 = lane & 15;

    __shared__ __align__(16) u16 Ks[64 * 128];      // [key][16 chunks] sw: c^(key&15)
    __shared__ __align__(16) u16 Vs[128 * 64];      // [d][8 chunks]    sw: c^(d&7)
    __shared__ __align__(16) u16 Ps[4][16 * PSTR];  // per-wave strip

    const u16* Kbase = QKV + (size_t)b * TT * 3072 + 2048 + kvh * HD;
    const u16* Vbase = Vt + (size_t)(b * 4 + kvh) * HD * TT;
    const float Cl = 0.12753102474f;  // (1/sqrt(128)) * log2(e)

    auto stageK = [&](int kt) {
#pragma unroll
        for (int i = 0; i < 4; i++) {
            int n = i * 256 + w * 64 + lane;
            int r = n >> 4, c = (n & 15) ^ (r & 15);
            gl_lds16(Kbase + (size_t)(kt * 64 + r) * 3072 + c * 8,
                     &Ks[(i * 256 + w * 64) * 8]);
        }
    };
    auto stageV = [&](int kt) {
#pragma unroll
        for (int i = 0; i < 4; i++) {
            int n = i * 256 + w * 64 + lane;
            int d = n >> 3, c = (n & 7) ^ (d & 7);
            gl_lds16(Vbase + (size_t)d * TT + kt * 64 + c * 8,
                     &Vs[(i * 256 + w * 64) * 8]);
        }
    };

    stageK(0);

    // Q fragments to registers (B-layout: l16 = q-row)
    short8 qf[4];
    {
        const u16* Qrow = QKV + ((size_t)b * TT + qb * 64 + w * 16 + l16) * 3072
                          + h * HD;
#pragma unroll
        for (int ks = 0; ks < 4; ks++)
            qf[ks] = *(const short8*)(Qrow + ks * 32 + quad * 8);
    }

    float4_t o[8];
#pragma unroll
    for (int i = 0; i < 8; i++) o[i] = (float4_t){0.f, 0.f, 0.f, 0.f};
    float mi = -1e30f, li = 0.f;
    const int qg = qb * 64 + w * 16 + l16;  // this lane's q-row (S^T col)

    for (int kt = 0; kt <= qb; kt++) {
        __syncthreads();        // B1: K[kt] landed; prev PV done reading Vs
        stageV(kt);             // async; lands under S^T + softmax

        // S^T = K·Q^T
        float4_t st[4];
#pragma unroll
        for (int nt = 0; nt < 4; nt++) st[nt] = (float4_t){0.f, 0.f, 0.f, 0.f};
#pragma unroll
        for (int ks = 0; ks < 4; ks++) {
            short8 af[4];
#pragma unroll
            for (int nt = 0; nt < 4; nt++)
                af[nt] = *(const short8*)&Ks[((nt * 16 + l16) * 16 +
                                             ((ks * 4 + quad) ^ l16)) * 8];
            __builtin_amdgcn_s_setprio(1);
#pragma unroll
            for (int nt = 0; nt < 4; nt++)
                st[nt] = __builtin_amdgcn_mfma_f32_16x16x32_bf16(
                    af[nt], qf[ks], st[nt], 0, 0, 0);
            __builtin_amdgcn_s_setprio(0);
        }

        // mask + softmax + pack
        if (kt == qb) {
#pragma unroll
            for (int nt = 0; nt < 4; nt++)
#pragma unroll
                for (int r = 0; r < 4; r++) {
                    int key = kt * 64 + nt * 16 + quad * 4 + r;
                    if (key > qg) st[nt][r] = -3e38f;
                }
        }
        float pm = -3e38f;
#pragma unroll
        for (int nt = 0; nt < 4; nt++)
#pragma unroll
            for (int r = 0; r < 4; r++) pm = fmaxf(pm, st[nt][r]);
        pm = fmaxf(pm, __shfl_xor(pm, 16, 64));
        pm = fmaxf(pm, __shfl_xor(pm, 32, 64));
        // T13 defer-max: threshold 62.7 raw = 8 in log2 -> P <= 2^8
        const bool need = !__all(pm - mi <= 62.7f);
        float alpha_v = 1.f;
        if (need) {
            float mnew = fmaxf(mi, pm);
            alpha_v = __builtin_amdgcn_exp2f((mi - mnew) * Cl);
            mi = mnew;
        }
        const float mC = mi * Cl;
        float rs = 0.f;
#pragma unroll
        for (int nt = 0; nt < 4; nt++)
#pragma unroll
            for (int r = 0; r < 4; r++) {
                float e = __builtin_amdgcn_exp2f(fmaf(st[nt][r], Cl, -mC));
                st[nt][r] = e;
                rs += e;
            }
        rs += __shfl_xor(rs, 16, 64);
        rs += __shfl_xor(rs, 32, 64);
        li = li * alpha_v + rs;

        // P -> strip (truncation-pack via v_perm, b64 writes)
#pragma unroll
        for (int nt = 0; nt < 4; nt++) {
            uint2 pk;
            pk.x = __builtin_amdgcn_perm(fbits(st[nt][1]), fbits(st[nt][0]), 0x07060302u);
            pk.y = __builtin_amdgcn_perm(fbits(st[nt][3]), fbits(st[nt][2]), 0x07060302u);
            *(uint2*)&Ps[w][l16 * PSTR + nt * 16 + quad * 4] = pk;
        }
        // rescale O only when the running max moved (o rows are q=quad*4+r)
        if (need) {
            float a_o[4];
#pragma unroll
            for (int r = 0; r < 4; r++) a_o[r] = __shfl(alpha_v, quad * 4 + r, 64);
#pragma unroll
            for (int n2 = 0; n2 < 8; n2++)
#pragma unroll
                for (int r = 0; r < 4; r++) o[n2][r] *= a_o[r];
        }

        __syncthreads();                 // B2: V[kt] landed; all Ks reads done
        if (kt < qb) stageK(kt + 1);     // overwrite Ks; lands at next B1

        // O += P·V
#pragma unroll
        for (int ks2 = 0; ks2 < 2; ks2++) {
            short8 ap = *(const short8*)&Ps[w][l16 * PSTR + ks2 * 32 + quad * 8];
            __builtin_amdgcn_s_setprio(1);
#pragma unroll
            for (int n2 = 0; n2 < 8; n2++) {
                short8 bv = *(const short8*)&Vs[((n2 * 16 + l16) * 8 +
                                                ((ks2 * 4 + quad) ^ (l16 & 7))) * 8];
                o[n2] = __builtin_amdgcn_mfma_f32_16x16x32_bf16(ap, bv, o[n2], 0, 0, 0);
            }
            __builtin_amdgcn_s_setprio(0);
        }
    }

    // epilogue
    float linv[4];
#pragma unroll
    for (int r = 0; r < 4; r++) linv[r] = 1.0f / __shfl(li, quad * 4 + r, 64);
    u16* Ob2 = O + ((size_t)b * TT + qb * 64 + w * 16) * TDIM + h * HD;
#pragma unroll
    for (int n2 = 0; n2 < 8; n2++)
#pragma unroll
        for (int r = 0; r < 4; r++)
            Ob2[(size_t)(quad * 4 + r) * TDIM + n2 * 16 + l16] =
                f2b(o[n2][r] * linv[r]);
}

// ---------------------------------------------------------------------------
extern "C" void kernel_launch(void* const* d_in, const int* in_sizes, int n_in,
                              void* d_out, int out_size, void* d_ws, size_t ws_size,
                              hipStream_t stream) {
    const float* x  = (const float*)d_in[0];
    const float* fc = (const float*)d_in[1];
    const float* fs = (const float*)d_in[2];
    const float* wq = (const float*)d_in[3];
    const float* wk = (const float*)d_in[4];
    const float* wv = (const float*)d_in[5];
    const float* wo = (const float*)d_in[6];
    float* out = (float*)d_out;

    char* ws = (char*)d_ws;
    size_t off = 0;
    auto alloc = [&](size_t bytes) -> void* {
        void* p = ws + off;
        off += (bytes + 255) & ~(size_t)255;
        return p;
    };
    u16* xb  = (u16*)alloc((size_t)4096 * 2048 * 2);  // x in bf16
    u16* WT  = (u16*)alloc((size_t)3072 * 2048 * 2);  // [wqT|wkT|wvT] N x K bf16
    u16* woT = (u16*)alloc((size_t)2048 * 2048 * 2);
    u16* QKV = (u16*)alloc((size_t)4096 * 3072 * 2);  // [Q|K|V] fused bf16 (roped)
    u16* Vtb = (u16*)alloc((size_t)4096 * 512 * 2);   // V^T per (b,kv): [d][t]
    u16* Ob  = (u16*)alloc((size_t)4096 * 2048 * 2);  // attention output bf16

    dim3 blk(256);
    // fused x-convert + all weight transposes (one launch)
    prep<<<dim3(8192 + 160 * 64), blk, 0, stream>>>(x, xb, wq, wk, wv, wo, WT, woT);
    // fused QKV projection with RoPE applied in the epilogue (Q|K cols only)
    gemm_bt<false, true><<<dim3(24, 32), blk, 0, stream>>>(
        xb, WT, QKV, 4096, 3072, 2048, fc, fs);
    transpose_v<<<dim3(64, 4, 8), blk, 0, stream>>>(QKV, Vtb);
    // 1024 blocks, 1D grid, globally longest-first (LPT); 3 blocks/CU
    attn<<<dim3(1024), blk, 0, stream>>>(QKV, Vtb, Ob);
    gemm_bt<true, false><<<dim3(16, 32), blk, 0, stream>>>(
        Ob, woT, out, 4096, 2048, 2048, nullptr, nullptr);
}

// Round 6
// 290.116 us; speedup vs baseline: 1.1682x; 1.0322x over previous
//
#include <hip/hip_runtime.h>

#define TB 2
#define TT 2048
#define TDIM 2048
#define NHEADS 16
#define KVHEADS 4
#define HD 128

typedef unsigned short u16;
typedef unsigned int u32;
typedef __attribute__((ext_vector_type(8))) short short8;
typedef __attribute__((ext_vector_type(4))) float float4_t;

__device__ __forceinline__ float b2f(u16 u) {
    union { u32 i; float f; } v; v.i = ((u32)u) << 16; return v.f;
}
__device__ __forceinline__ u16 f2b(float f) {
    union { float f; u32 i; } v; v.f = f;
    u32 r = (v.i + 0x7FFFu + ((v.i >> 16) & 1u)) >> 16;
    return (u16)r;
}
__device__ __forceinline__ u32 fbits(float f) {
    union { float f; u32 i; } v; v.f = f; return v.i;
}

// async global->LDS, 16B/lane; LDS dest must be wave-uniform base (+lane*16)
__device__ __forceinline__ void gl_lds16(const void* g, void* l) {
    __builtin_amdgcn_global_load_lds((const __attribute__((address_space(1))) void*)g,
                                     (__attribute__((address_space(3))) void*)l, 16, 0, 0);
}

// ---------------------------------------------------------------------------
// bf16 GEMM: C[M,N] = A[M,K] * B[K,N], B pre-transposed (BT is N x K, bf16).
// 128x128 tile, BK=64, 4 waves (2x2), m97 structure. Optional fused RoPE.
// NOTE: 256^2 8-phase template was tried (R1): per-active-CU parity with this
// kernel (686 vs 718 TF) but N=3072 gives only 192 blocks < 256 CUs -> -25%.
// This shape structurally favors the 768-block 128^2 layout (3 blocks/CU).
// ---------------------------------------------------------------------------
template <bool F32OUT, bool ROPE>
__global__ __launch_bounds__(256, 3)
void gemm_bt(const u16* __restrict__ A, const u16* __restrict__ BT,
             void* __restrict__ Cv, int M, int N, int K,
             const float* __restrict__ fc, const float* __restrict__ fs) {
    __shared__ __align__(16) u16 As[128 * 64];
    __shared__ __align__(16) u16 Bs[128 * 64];
    const int tid  = threadIdx.x;
    const int wave = tid >> 6, lane = tid & 63;
    const int quad = lane >> 4, l16 = lane & 15;
    const int wm = wave >> 1, wn = wave & 1;
    const int row0 = blockIdx.y * 128, col0 = blockIdx.x * 128;

    float4_t acc[4][4];
#pragma unroll
    for (int i = 0; i < 4; i++)
#pragma unroll
        for (int j = 0; j < 4; j++) acc[i][j] = (float4_t){0.f, 0.f, 0.f, 0.f};

    for (int kk = 0; kk < K; kk += 64) {
        __syncthreads();
#pragma unroll
        for (int i = 0; i < 4; i++) {
            int n = i * 256 + wave * 64 + lane;
            int r = n >> 3, c = (n & 7) ^ (r & 7);
            gl_lds16(A  + (size_t)(row0 + r) * K + kk + c * 8, &As[(i * 256 + wave * 64) * 8]);
            gl_lds16(BT + (size_t)(col0 + r) * K + kk + c * 8, &Bs[(i * 256 + wave * 64) * 8]);
        }
        __syncthreads();
#pragma unroll
        for (int ks = 0; ks < 2; ks++) {
            short8 af[4], bf[4];
#pragma unroll
            for (int mt = 0; mt < 4; mt++) {
                int m = wm * 64 + mt * 16 + l16;
                af[mt] = *(const short8*)&As[(m * 8 + ((ks * 4 + quad) ^ (l16 & 7))) * 8];
            }
#pragma unroll
            for (int nt = 0; nt < 4; nt++) {
                int n = wn * 64 + nt * 16 + l16;
                bf[nt] = *(const short8*)&Bs[(n * 8 + ((ks * 4 + quad) ^ (l16 & 7))) * 8];
            }
#pragma unroll
            for (int mt = 0; mt < 4; mt++)
#pragma unroll
                for (int nt = 0; nt < 4; nt++)
                    acc[mt][nt] = __builtin_amdgcn_mfma_f32_16x16x32_bf16(
                        af[mt], bf[nt], acc[mt][nt], 0, 0, 0);
        }
    }
    // epilogue: C/D layout col=lane&15, row=quad*4+reg  [m89/m91]
    const bool do_rope = ROPE && (col0 < 2560);
#pragma unroll
    for (int mt = 0; mt < 4; mt++)
#pragma unroll
        for (int nt = 0; nt < 4; nt++)
#pragma unroll
            for (int r = 0; r < 4; r++) {
                int row = row0 + wm * 64 + mt * 16 + quad * 4 + r;
                int col = col0 + wn * 64 + nt * 16 + l16;
                float v = acc[mt][nt][r];
                if (ROPE && do_rope) {
                    float other = __shfl_xor(v, 1, 64);
                    int t = row & (TT - 1);
                    int i0 = (col & (HD - 1)) >> 1;
                    float c = fc[t * 64 + i0], s = fs[t * 64 + i0];
                    v = (col & 1) ? fmaf(v, c, other * s) : fmaf(v, c, -other * s);
                }
                if (F32OUT)
                    ((float*)Cv)[(size_t)row * N + col] = v;
                else
                    ((u16*)Cv)[(size_t)row * N + col] = f2b(v);
            }
}

// ---------------------------------------------------------------------------
// Fused prep: x fp32->bf16 (blocks 0..8191) + all four weight transposes
// (fp32 KxN -> bf16 NxK, blocks 8192..13311).
// R6: weight transpose widened to 64-row x 32-col tiles so each output row
// write is a contiguous 128 B short8 segment (was 64 B) -- transposed-write
// coalescing was the bottleneck of this memory-bound kernel.
// LDS tile [col 32][row 72pad]: 144 B stride keeps short8 reads 16B-aligned.
// ---------------------------------------------------------------------------
__global__ void prep(const float* __restrict__ x, u16* __restrict__ xb,
                     const float* __restrict__ wq, const float* __restrict__ wk,
                     const float* __restrict__ wv, const float* __restrict__ wo,
                     u16* __restrict__ WT, u16* __restrict__ woT) {
    const int bid = blockIdx.x;
    if (bid < 8192) {
        size_t i = ((size_t)bid * 256 + threadIdx.x) * 4;
        float4 v = *(const float4*)(x + i);
        ushort4 o;
        o.x = f2b(v.x); o.y = f2b(v.y); o.z = f2b(v.z); o.w = f2b(v.w);
        *(ushort4*)(xb + i) = o;
        return;
    }
    const int rem = bid - 8192;
    const int bx = rem % 160;      // col-tile (32 cols each), as before
    const int by = rem / 160;      // 64-row groups: 0..31
    const float* in; u16* out; int cols, cx;
    if (bx < 64)      { in = wq; out = WT;                         cols = 2048; cx = bx; }
    else if (bx < 80) { in = wk; out = WT + (size_t)2048 * 2048;   cols = 512;  cx = bx - 64; }
    else if (bx < 96) { in = wv; out = WT + (size_t)2560 * 2048;   cols = 512;  cx = bx - 80; }
    else              { in = wo; out = woT;                        cols = 2048; cx = bx - 96; }
    const int rows = 2048;
    __shared__ u16 tile[32][72];   // [col][row], padded: 144 B stride
    const int c0 = cx * 32, r0 = by * 64;
    const int tx = threadIdx.x & 31, ty = threadIdx.x >> 5;  // tx: col, ty: row-group
#pragma unroll
    for (int i = 0; i < 8; i++) {
        int r = ty * 8 + i;        // 0..63
        tile[tx][r] = f2b(in[(size_t)(r0 + r) * cols + c0 + tx]);
    }
    __syncthreads();
    // store: thread = (c = tid>>3, rc = tid&7); 8 threads cover one output
    // row's 64 u16 = 128 B contiguous.
    const int c = threadIdx.x >> 3, rc = threadIdx.x & 7;
    *(short8*)&out[(size_t)(c0 + c) * rows + r0 + rc * 8] =
        *(const short8*)&tile[c][rc * 8];
}

// V slice of QKV (bf16, cols 2560 + kv*128) -> Vt[b][kv][d][t] (bf16)
// R6: 64-t x 32-d tiles, 128 B contiguous short8 writes per output d-row.
__global__ void transpose_v(const u16* __restrict__ QKV, u16* __restrict__ Vt) {
    int z = blockIdx.z, b = z >> 2, kv = z & 3;
    const u16* in = QKV + (size_t)b * TT * 3072 + 2560 + kv * HD;  // (t,d)
    u16* out = Vt + (size_t)z * HD * TT;                           // (d,t)
    __shared__ u16 tile[32][72];   // [d][t], padded
    const int t0 = blockIdx.x * 64, d0 = blockIdx.y * 32;
    const int tx = threadIdx.x & 31, ty = threadIdx.x >> 5;
#pragma unroll
    for (int i = 0; i < 8; i++) {
        int r = ty * 8 + i;        // t-local 0..63
        tile[tx][r] = in[(size_t)(t0 + r) * 3072 + d0 + tx];
    }
    __syncthreads();
    const int c = threadIdx.x >> 3, rc = threadIdx.x & 7;
    *(short8*)&out[(size_t)(d0 + c) * TT + t0 + rc * 8] =
        *(const short8*)&tile[c][rc * 8];
}

// ---------------------------------------------------------------------------
// Causal flash attention v9 (unchanged from R5): GLOBAL longest-first (LPT)
// 1D grid; bid>>5 = q-selector (descending length), bid&31 = (b,head).
// Single-buffer K (stageK(kt+1) after B2 -- all Ks reads complete before B2),
// async V stage under S^T+softmax, setprio (T5), defer-max (T13).
// LDS 41984 B, 3 blocks/CU. Same-(b,kvh) blocks 32 apart -> same XCD.
// ---------------------------------------------------------------------------
#define PSTR 72
__global__ __launch_bounds__(256, 3)
void attn(const u16* __restrict__ QKV, const u16* __restrict__ Vt,
          u16* __restrict__ O) {
    const int bid = blockIdx.x;      // 0..1023, 1D
    const int qb  = 31 - (bid >> 5); // q-tile, globally longest first
    const int y   = bid & 31;        // (b, head): b = y>>4, h = y&15
    const int b   = y >> 4;
    const int h   = y & 15;
    const int kvh = h >> 2;
    const int tid = threadIdx.x, w = tid >> 6, lane = tid & 63;
    const int quad = lane >> 4, l16 = lane & 15;

    __shared__ __align__(16) u16 Ks[64 * 128];      // [key][16 chunks] sw: c^(key&15)
    __shared__ __align__(16) u16 Vs[128 * 64];      // [d][8 chunks]    sw: c^(d&7)
    __shared__ __align__(16) u16 Ps[4][16 * PSTR];  // per-wave strip

    const u16* Kbase = QKV + (size_t)b * TT * 3072 + 2048 + kvh * HD;
    const u16* Vbase = Vt + (size_t)(b * 4 + kvh) * HD * TT;
    const float Cl = 0.12753102474f;  // (1/sqrt(128)) * log2(e)

    auto stageK = [&](int kt) {
#pragma unroll
        for (int i = 0; i < 4; i++) {
            int n = i * 256 + w * 64 + lane;
            int r = n >> 4, c = (n & 15) ^ (r & 15);
            gl_lds16(Kbase + (size_t)(kt * 64 + r) * 3072 + c * 8,
                     &Ks[(i * 256 + w * 64) * 8]);
        }
    };
    auto stageV = [&](int kt) {
#pragma unroll
        for (int i = 0; i < 4; i++) {
            int n = i * 256 + w * 64 + lane;
            int d = n >> 3, c = (n & 7) ^ (d & 7);
            gl_lds16(Vbase + (size_t)d * TT + kt * 64 + c * 8,
                     &Vs[(i * 256 + w * 64) * 8]);
        }
    };

    stageK(0);

    // Q fragments to registers (B-layout: l16 = q-row)
    short8 qf[4];
    {
        const u16* Qrow = QKV + ((size_t)b * TT + qb * 64 + w * 16 + l16) * 3072
                          + h * HD;
#pragma unroll
        for (int ks = 0; ks < 4; ks++)
            qf[ks] = *(const short8*)(Qrow + ks * 32 + quad * 8);
    }

    float4_t o[8];
#pragma unroll
    for (int i = 0; i < 8; i++) o[i] = (float4_t){0.f, 0.f, 0.f, 0.f};
    float mi = -1e30f, li = 0.f;
    const int qg = qb * 64 + w * 16 + l16;  // this lane's q-row (S^T col)

    for (int kt = 0; kt <= qb; kt++) {
        __syncthreads();        // B1: K[kt] landed; prev PV done reading Vs
        stageV(kt);             // async; lands under S^T + softmax

        // S^T = K·Q^T
        float4_t st[4];
#pragma unroll
        for (int nt = 0; nt < 4; nt++) st[nt] = (float4_t){0.f, 0.f, 0.f, 0.f};
#pragma unroll
        for (int ks = 0; ks < 4; ks++) {
            short8 af[4];
#pragma unroll
            for (int nt = 0; nt < 4; nt++)
                af[nt] = *(const short8*)&Ks[((nt * 16 + l16) * 16 +
                                             ((ks * 4 + quad) ^ l16)) * 8];
            __builtin_amdgcn_s_setprio(1);
#pragma unroll
            for (int nt = 0; nt < 4; nt++)
                st[nt] = __builtin_amdgcn_mfma_f32_16x16x32_bf16(
                    af[nt], qf[ks], st[nt], 0, 0, 0);
            __builtin_amdgcn_s_setprio(0);
        }

        // mask + softmax + pack
        if (kt == qb) {
#pragma unroll
            for (int nt = 0; nt < 4; nt++)
#pragma unroll
                for (int r = 0; r < 4; r++) {
                    int key = kt * 64 + nt * 16 + quad * 4 + r;
                    if (key > qg) st[nt][r] = -3e38f;
                }
        }
        float pm = -3e38f;
#pragma unroll
        for (int nt = 0; nt < 4; nt++)
#pragma unroll
            for (int r = 0; r < 4; r++) pm = fmaxf(pm, st[nt][r]);
        pm = fmaxf(pm, __shfl_xor(pm, 16, 64));
        pm = fmaxf(pm, __shfl_xor(pm, 32, 64));
        // T13 defer-max: threshold 62.7 raw = 8 in log2 -> P <= 2^8
        const bool need = !__all(pm - mi <= 62.7f);
        float alpha_v = 1.f;
        if (need) {
            float mnew = fmaxf(mi, pm);
            alpha_v = __builtin_amdgcn_exp2f((mi - mnew) * Cl);
            mi = mnew;
        }
        const float mC = mi * Cl;
        float rs = 0.f;
#pragma unroll
        for (int nt = 0; nt < 4; nt++)
#pragma unroll
            for (int r = 0; r < 4; r++) {
                float e = __builtin_amdgcn_exp2f(fmaf(st[nt][r], Cl, -mC));
                st[nt][r] = e;
                rs += e;
            }
        rs += __shfl_xor(rs, 16, 64);
        rs += __shfl_xor(rs, 32, 64);
        li = li * alpha_v + rs;

        // P -> strip (truncation-pack via v_perm, b64 writes)
#pragma unroll
        for (int nt = 0; nt < 4; nt++) {
            uint2 pk;
            pk.x = __builtin_amdgcn_perm(fbits(st[nt][1]), fbits(st[nt][0]), 0x07060302u);
            pk.y = __builtin_amdgcn_perm(fbits(st[nt][3]), fbits(st[nt][2]), 0x07060302u);
            *(uint2*)&Ps[w][l16 * PSTR + nt * 16 + quad * 4] = pk;
        }
        // rescale O only when the running max moved (o rows are q=quad*4+r)
        if (need) {
            float a_o[4];
#pragma unroll
            for (int r = 0; r < 4; r++) a_o[r] = __shfl(alpha_v, quad * 4 + r, 64);
#pragma unroll
            for (int n2 = 0; n2 < 8; n2++)
#pragma unroll
                for (int r = 0; r < 4; r++) o[n2][r] *= a_o[r];
        }

        __syncthreads();                 // B2: V[kt] landed; all Ks reads done
        if (kt < qb) stageK(kt + 1);     // overwrite Ks; lands at next B1

        // O += P·V
#pragma unroll
        for (int ks2 = 0; ks2 < 2; ks2++) {
            short8 ap = *(const short8*)&Ps[w][l16 * PSTR + ks2 * 32 + quad * 8];
            __builtin_amdgcn_s_setprio(1);
#pragma unroll
            for (int n2 = 0; n2 < 8; n2++) {
                short8 bv = *(const short8*)&Vs[((n2 * 16 + l16) * 8 +
                                                ((ks2 * 4 + quad) ^ (l16 & 7))) * 8];
                o[n2] = __builtin_amdgcn_mfma_f32_16x16x32_bf16(ap, bv, o[n2], 0, 0, 0);
            }
            __builtin_amdgcn_s_setprio(0);
        }
    }

    // epilogue
    float linv[4];
#pragma unroll
    for (int r = 0; r < 4; r++) linv[r] = 1.0f / __shfl(li, quad * 4 + r, 64);
    u16* Ob2 = O + ((size_t)b * TT + qb * 64 + w * 16) * TDIM + h * HD;
#pragma unroll
    for (int n2 = 0; n2 < 8; n2++)
#pragma unroll
        for (int r = 0; r < 4; r++)
            Ob2[(size_t)(quad * 4 + r) * TDIM + n2 * 16 + l16] =
                f2b(o[n2][r] * linv[r]);
}

// ---------------------------------------------------------------------------
extern "C" void kernel_launch(void* const* d_in, const int* in_sizes, int n_in,
                              void* d_out, int out_size, void* d_ws, size_t ws_size,
                              hipStream_t stream) {
    const float* x  = (const float*)d_in[0];
    const float* fc = (const float*)d_in[1];
    const float* fs = (const float*)d_in[2];
    const float* wq = (const float*)d_in[3];
    const float* wk = (const float*)d_in[4];
    const float* wv = (const float*)d_in[5];
    const float* wo = (const float*)d_in[6];
    float* out = (float*)d_out;

    char* ws = (char*)d_ws;
    size_t off = 0;
    auto alloc = [&](size_t bytes) -> void* {
        void* p = ws + off;
        off += (bytes + 255) & ~(size_t)255;
        return p;
    };
    u16* xb  = (u16*)alloc((size_t)4096 * 2048 * 2);  // x in bf16
    u16* WT  = (u16*)alloc((size_t)3072 * 2048 * 2);  // [wqT|wkT|wvT] N x K bf16
    u16* woT = (u16*)alloc((size_t)2048 * 2048 * 2);
    u16* QKV = (u16*)alloc((size_t)4096 * 3072 * 2);  // [Q|K|V] fused bf16 (roped)
    u16* Vtb = (u16*)alloc((size_t)4096 * 512 * 2);   // V^T per (b,kv): [d][t]
    u16* Ob  = (u16*)alloc((size_t)4096 * 2048 * 2);  // attention output bf16

    dim3 blk(256);
    // fused x-convert (8192 blocks) + weight transposes (160 x 32 tiles)
    prep<<<dim3(8192 + 160 * 32), blk, 0, stream>>>(x, xb, wq, wk, wv, wo, WT, woT);
    // fused QKV projection with RoPE applied in the epilogue (Q|K cols only)
    gemm_bt<false, true><<<dim3(24, 32), blk, 0, stream>>>(
        xb, WT, QKV, 4096, 3072, 2048, fc, fs);
    transpose_v<<<dim3(32, 4, 8), blk, 0, stream>>>(QKV, Vtb);
    // 1024 blocks, 1D grid, globally longest-first (LPT); 3 blocks/CU
    attn<<<dim3(1024), blk, 0, stream>>>(QKV, Vtb, Ob);
    gemm_bt<true, false><<<dim3(16, 32), blk, 0, stream>>>(
        Ob, woT, out, 4096, 2048, 2048, nullptr, nullptr);
}

// Round 7
// 289.626 us; speedup vs baseline: 1.1702x; 1.0017x over previous
//
#include <hip/hip_runtime.h>

#define TB 2
#define TT 2048
#define TDIM 2048
#define NHEADS 16
#define KVHEADS 4
#define HD 128

typedef unsigned short u16;
typedef unsigned int u32;
typedef __attribute__((ext_vector_type(8))) short short8;
typedef __attribute__((ext_vector_type(4))) float float4_t;

__device__ __forceinline__ float b2f(u16 u) {
    union { u32 i; float f; } v; v.i = ((u32)u) << 16; return v.f;
}
__device__ __forceinline__ u16 f2b(float f) {
    union { float f; u32 i; } v; v.f = f;
    u32 r = (v.i + 0x7FFFu + ((v.i >> 16) & 1u)) >> 16;
    return (u16)r;
}
__device__ __forceinline__ u32 fbits(float f) {
    union { float f; u32 i; } v; v.f = f; return v.i;
}

// async global->LDS, 16B/lane; LDS dest must be wave-uniform base (+lane*16)
__device__ __forceinline__ void gl_lds16(const void* g, void* l) {
    __builtin_amdgcn_global_load_lds((const __attribute__((address_space(1))) void*)g,
                                     (__attribute__((address_space(3))) void*)l, 16, 0, 0);
}

// ---------------------------------------------------------------------------
// bf16 GEMM: C[M,N] = A[M,K] * B[K,N], B pre-transposed (BT is N x K, bf16).
// 128x128 tile, BK=64, 4 waves (2x2), m97 structure. Optional fused RoPE.
// Used for QKV: 24x32 = 768 blocks = 3/CU = 12 waves/CU (proven 70.5us/30%).
// ---------------------------------------------------------------------------
template <bool F32OUT, bool ROPE>
__global__ __launch_bounds__(256, 3)
void gemm_bt(const u16* __restrict__ A, const u16* __restrict__ BT,
             void* __restrict__ Cv, int M, int N, int K,
             const float* __restrict__ fc, const float* __restrict__ fs) {
    __shared__ __align__(16) u16 As[128 * 64];
    __shared__ __align__(16) u16 Bs[128 * 64];
    const int tid  = threadIdx.x;
    const int wave = tid >> 6, lane = tid & 63;
    const int quad = lane >> 4, l16 = lane & 15;
    const int wm = wave >> 1, wn = wave & 1;
    const int row0 = blockIdx.y * 128, col0 = blockIdx.x * 128;

    float4_t acc[4][4];
#pragma unroll
    for (int i = 0; i < 4; i++)
#pragma unroll
        for (int j = 0; j < 4; j++) acc[i][j] = (float4_t){0.f, 0.f, 0.f, 0.f};

    for (int kk = 0; kk < K; kk += 64) {
        __syncthreads();
#pragma unroll
        for (int i = 0; i < 4; i++) {
            int n = i * 256 + wave * 64 + lane;
            int r = n >> 3, c = (n & 7) ^ (r & 7);
            gl_lds16(A  + (size_t)(row0 + r) * K + kk + c * 8, &As[(i * 256 + wave * 64) * 8]);
            gl_lds16(BT + (size_t)(col0 + r) * K + kk + c * 8, &Bs[(i * 256 + wave * 64) * 8]);
        }
        __syncthreads();
#pragma unroll
        for (int ks = 0; ks < 2; ks++) {
            short8 af[4], bf[4];
#pragma unroll
            for (int mt = 0; mt < 4; mt++) {
                int m = wm * 64 + mt * 16 + l16;
                af[mt] = *(const short8*)&As[(m * 8 + ((ks * 4 + quad) ^ (l16 & 7))) * 8];
            }
#pragma unroll
            for (int nt = 0; nt < 4; nt++) {
                int n = wn * 64 + nt * 16 + l16;
                bf[nt] = *(const short8*)&Bs[(n * 8 + ((ks * 4 + quad) ^ (l16 & 7))) * 8];
            }
#pragma unroll
            for (int mt = 0; mt < 4; mt++)
#pragma unroll
                for (int nt = 0; nt < 4; nt++)
                    acc[mt][nt] = __builtin_amdgcn_mfma_f32_16x16x32_bf16(
                        af[mt], bf[nt], acc[mt][nt], 0, 0, 0);
        }
    }
    // epilogue: C/D layout col=lane&15, row=quad*4+reg  [m89/m91]
    const bool do_rope = ROPE && (col0 < 2560);
#pragma unroll
    for (int mt = 0; mt < 4; mt++)
#pragma unroll
        for (int nt = 0; nt < 4; nt++)
#pragma unroll
            for (int r = 0; r < 4; r++) {
                int row = row0 + wm * 64 + mt * 16 + quad * 4 + r;
                int col = col0 + wn * 64 + nt * 16 + l16;
                float v = acc[mt][nt][r];
                if (ROPE && do_rope) {
                    float other = __shfl_xor(v, 1, 64);
                    int t = row & (TT - 1);
                    int i0 = (col & (HD - 1)) >> 1;
                    float c = fc[t * 64 + i0], s = fs[t * 64 + i0];
                    v = (col & 1) ? fmaf(v, c, other * s) : fmaf(v, c, -other * s);
                }
                if (F32OUT)
                    ((float*)Cv)[(size_t)row * N + col] = v;
                else
                    ((u16*)Cv)[(size_t)row * N + col] = f2b(v);
            }
}

// ---------------------------------------------------------------------------
// 8-WAVE variant of the m97 structure for grids with < 768 natural blocks.
// R6 theory: out-proj (M=4096,N=2048 -> 512 blocks) runs at 2 blocks/CU = 8
// waves/CU in the 4-wave kernel; m132 showed the m97 barrier drain collapses
// to ~508/550 TF at 8 waves. This kernel keeps the 128^2 tile (same staging
// economics, same LDS 32KB, same swizzle) but uses 8 waves of 32x64 tiles:
// 2 blocks/CU x 8 waves = 16 waves/CU. VGPR ~76 (acc 32 + frags 24) <= 128.
// ---------------------------------------------------------------------------
template <bool F32OUT>
__global__ __launch_bounds__(512, 4)
void gemm_bt8w(const u16* __restrict__ A, const u16* __restrict__ BT,
               void* __restrict__ Cv, int M, int N, int K) {
    __shared__ __align__(16) u16 As[128 * 64];
    __shared__ __align__(16) u16 Bs[128 * 64];
    const int tid  = threadIdx.x;
    const int w    = tid >> 6, lane = tid & 63;
    const int quad = lane >> 4, l16 = lane & 15;
    const int wm = w >> 1, wn = w & 1;      // 4x2 wave grid, wave-tile 32x64
    const int row0 = blockIdx.y * 128, col0 = blockIdx.x * 128;

    float4_t acc[2][4];
#pragma unroll
    for (int i = 0; i < 2; i++)
#pragma unroll
        for (int j = 0; j < 4; j++) acc[i][j] = (float4_t){0.f, 0.f, 0.f, 0.f};

    for (int kk = 0; kk < K; kk += 64) {
        __syncthreads();
#pragma unroll
        for (int j = 0; j < 2; j++) {
            int n = j * 512 + w * 64 + lane;   // 0..1023 chunk slots
            int r = n >> 3, c = (n & 7) ^ (r & 7);
            gl_lds16(A  + (size_t)(row0 + r) * K + kk + c * 8, &As[(j * 512 + w * 64) * 8]);
            gl_lds16(BT + (size_t)(col0 + r) * K + kk + c * 8, &Bs[(j * 512 + w * 64) * 8]);
        }
        __syncthreads();
#pragma unroll
        for (int ks = 0; ks < 2; ks++) {
            short8 af[2], bf[4];
#pragma unroll
            for (int mt = 0; mt < 2; mt++) {
                int m = wm * 32 + mt * 16 + l16;
                af[mt] = *(const short8*)&As[(m * 8 + ((ks * 4 + quad) ^ (l16 & 7))) * 8];
            }
#pragma unroll
            for (int nt = 0; nt < 4; nt++) {
                int n = wn * 64 + nt * 16 + l16;
                bf[nt] = *(const short8*)&Bs[(n * 8 + ((ks * 4 + quad) ^ (l16 & 7))) * 8];
            }
#pragma unroll
            for (int mt = 0; mt < 2; mt++)
#pragma unroll
                for (int nt = 0; nt < 4; nt++)
                    acc[mt][nt] = __builtin_amdgcn_mfma_f32_16x16x32_bf16(
                        af[mt], bf[nt], acc[mt][nt], 0, 0, 0);
        }
    }
    // epilogue: C/D layout col=lane&15, row=quad*4+reg
#pragma unroll
    for (int mt = 0; mt < 2; mt++)
#pragma unroll
        for (int nt = 0; nt < 4; nt++)
#pragma unroll
            for (int r = 0; r < 4; r++) {
                int row = row0 + wm * 32 + mt * 16 + quad * 4 + r;
                int col = col0 + wn * 64 + nt * 16 + l16;
                float v = acc[mt][nt][r];
                if (F32OUT)
                    ((float*)Cv)[(size_t)row * N + col] = v;
                else
                    ((u16*)Cv)[(size_t)row * N + col] = f2b(v);
            }
}

// ---------------------------------------------------------------------------
// Fused prep: x fp32->bf16 (blocks 0..8191) + all four weight transposes
// (64-row x 32-col tiles; 128 B contiguous short8 output-row writes).
// ---------------------------------------------------------------------------
__global__ void prep(const float* __restrict__ x, u16* __restrict__ xb,
                     const float* __restrict__ wq, const float* __restrict__ wk,
                     const float* __restrict__ wv, const float* __restrict__ wo,
                     u16* __restrict__ WT, u16* __restrict__ woT) {
    const int bid = blockIdx.x;
    if (bid < 8192) {
        size_t i = ((size_t)bid * 256 + threadIdx.x) * 4;
        float4 v = *(const float4*)(x + i);
        ushort4 o;
        o.x = f2b(v.x); o.y = f2b(v.y); o.z = f2b(v.z); o.w = f2b(v.w);
        *(ushort4*)(xb + i) = o;
        return;
    }
    const int rem = bid - 8192;
    const int bx = rem % 160;      // col-tile (32 cols each)
    const int by = rem / 160;      // 64-row groups: 0..31
    const float* in; u16* out; int cols, cx;
    if (bx < 64)      { in = wq; out = WT;                         cols = 2048; cx = bx; }
    else if (bx < 80) { in = wk; out = WT + (size_t)2048 * 2048;   cols = 512;  cx = bx - 64; }
    else if (bx < 96) { in = wv; out = WT + (size_t)2560 * 2048;   cols = 512;  cx = bx - 80; }
    else              { in = wo; out = woT;                        cols = 2048; cx = bx - 96; }
    const int rows = 2048;
    __shared__ u16 tile[32][72];   // [col][row], padded: 144 B stride
    const int c0 = cx * 32, r0 = by * 64;
    const int tx = threadIdx.x & 31, ty = threadIdx.x >> 5;
#pragma unroll
    for (int i = 0; i < 8; i++) {
        int r = ty * 8 + i;        // 0..63
        tile[tx][r] = f2b(in[(size_t)(r0 + r) * cols + c0 + tx]);
    }
    __syncthreads();
    const int c = threadIdx.x >> 3, rc = threadIdx.x & 7;
    *(short8*)&out[(size_t)(c0 + c) * rows + r0 + rc * 8] =
        *(const short8*)&tile[c][rc * 8];
}

// V slice of QKV (bf16, cols 2560 + kv*128) -> Vt[b][kv][d][t] (bf16)
__global__ void transpose_v(const u16* __restrict__ QKV, u16* __restrict__ Vt) {
    int z = blockIdx.z, b = z >> 2, kv = z & 3;
    const u16* in = QKV + (size_t)b * TT * 3072 + 2560 + kv * HD;  // (t,d)
    u16* out = Vt + (size_t)z * HD * TT;                           // (d,t)
    __shared__ u16 tile[32][72];   // [d][t], padded
    const int t0 = blockIdx.x * 64, d0 = blockIdx.y * 32;
    const int tx = threadIdx.x & 31, ty = threadIdx.x >> 5;
#pragma unroll
    for (int i = 0; i < 8; i++) {
        int r = ty * 8 + i;        // t-local 0..63
        tile[tx][r] = in[(size_t)(t0 + r) * 3072 + d0 + tx];
    }
    __syncthreads();
    const int c = threadIdx.x >> 3, rc = threadIdx.x & 7;
    *(short8*)&out[(size_t)(d0 + c) * TT + t0 + rc * 8] =
        *(const short8*)&tile[c][rc * 8];
}

// ---------------------------------------------------------------------------
// Causal flash attention v9 (unchanged from R5/R6): GLOBAL longest-first
// (LPT) 1D grid; bid>>5 = q-selector (descending length), bid&31 = (b,head).
// Single-buffer K, async V stage under S^T+softmax, setprio (T5),
// defer-max (T13). LDS 41984 B, 3 blocks/CU = 12 waves/CU.
// ---------------------------------------------------------------------------
#define PSTR 72
__global__ __launch_bounds__(256, 3)
void attn(const u16* __restrict__ QKV, const u16* __restrict__ Vt,
          u16* __restrict__ O) {
    const int bid = blockIdx.x;      // 0..1023, 1D
    const int qb  = 31 - (bid >> 5); // q-tile, globally longest first
    const int y   = bid & 31;        // (b, head): b = y>>4, h = y&15
    const int b   = y >> 4;
    const int h   = y & 15;
    const int kvh = h >> 2;
    const int tid = threadIdx.x, w = tid >> 6, lane = tid & 63;
    const int quad = lane >> 4, l16 = lane & 15;

    __shared__ __align__(16) u16 Ks[64 * 128];      // [key][16 chunks] sw: c^(key&15)
    __shared__ __align__(16) u16 Vs[128 * 64];      // [d][8 chunks]    sw: c^(d&7)
    __shared__ __align__(16) u16 Ps[4][16 * PSTR];  // per-wave strip

    const u16* Kbase = QKV + (size_t)b * TT * 3072 + 2048 + kvh * HD;
    const u16* Vbase = Vt + (size_t)(b * 4 + kvh) * HD * TT;
    const float Cl = 0.12753102474f;  // (1/sqrt(128)) * log2(e)

    auto stageK = [&](int kt) {
#pragma unroll
        for (int i = 0; i < 4; i++) {
            int n = i * 256 + w * 64 + lane;
            int r = n >> 4, c = (n & 15) ^ (r & 15);
            gl_lds16(Kbase + (size_t)(kt * 64 + r) * 3072 + c * 8,
                     &Ks[(i * 256 + w * 64) * 8]);
        }
    };
    auto stageV = [&](int kt) {
#pragma unroll
        for (int i = 0; i < 4; i++) {
            int n = i * 256 + w * 64 + lane;
            int d = n >> 3, c = (n & 7) ^ (d & 7);
            gl_lds16(Vbase + (size_t)d * TT + kt * 64 + c * 8,
                     &Vs[(i * 256 + w * 64) * 8]);
        }
    };

    stageK(0);

    // Q fragments to registers (B-layout: l16 = q-row)
    short8 qf[4];
    {
        const u16* Qrow = QKV + ((size_t)b * TT + qb * 64 + w * 16 + l16) * 3072
                          + h * HD;
#pragma unroll
        for (int ks = 0; ks < 4; ks++)
            qf[ks] = *(const short8*)(Qrow + ks * 32 + quad * 8);
    }

    float4_t o[8];
#pragma unroll
    for (int i = 0; i < 8; i++) o[i] = (float4_t){0.f, 0.f, 0.f, 0.f};
    float mi = -1e30f, li = 0.f;
    const int qg = qb * 64 + w * 16 + l16;  // this lane's q-row (S^T col)

    for (int kt = 0; kt <= qb; kt++) {
        __syncthreads();        // B1: K[kt] landed; prev PV done reading Vs
        stageV(kt);             // async; lands under S^T + softmax

        // S^T = K·Q^T
        float4_t st[4];
#pragma unroll
        for (int nt = 0; nt < 4; nt++) st[nt] = (float4_t){0.f, 0.f, 0.f, 0.f};
#pragma unroll
        for (int ks = 0; ks < 4; ks++) {
            short8 af[4];
#pragma unroll
            for (int nt = 0; nt < 4; nt++)
                af[nt] = *(const short8*)&Ks[((nt * 16 + l16) * 16 +
                                             ((ks * 4 + quad) ^ l16)) * 8];
            __builtin_amdgcn_s_setprio(1);
#pragma unroll
            for (int nt = 0; nt < 4; nt++)
                st[nt] = __builtin_amdgcn_mfma_f32_16x16x32_bf16(
                    af[nt], qf[ks], st[nt], 0, 0, 0);
            __builtin_amdgcn_s_setprio(0);
        }

        // mask + softmax + pack
        if (kt == qb) {
#pragma unroll
            for (int nt = 0; nt < 4; nt++)
#pragma unroll
                for (int r = 0; r < 4; r++) {
                    int key = kt * 64 + nt * 16 + quad * 4 + r;
                    if (key > qg) st[nt][r] = -3e38f;
                }
        }
        float pm = -3e38f;
#pragma unroll
        for (int nt = 0; nt < 4; nt++)
#pragma unroll
            for (int r = 0; r < 4; r++) pm = fmaxf(pm, st[nt][r]);
        pm = fmaxf(pm, __shfl_xor(pm, 16, 64));
        pm = fmaxf(pm, __shfl_xor(pm, 32, 64));
        // T13 defer-max: threshold 62.7 raw = 8 in log2 -> P <= 2^8
        const bool need = !__all(pm - mi <= 62.7f);
        float alpha_v = 1.f;
        if (need) {
            float mnew = fmaxf(mi, pm);
            alpha_v = __builtin_amdgcn_exp2f((mi - mnew) * Cl);
            mi = mnew;
        }
        const float mC = mi * Cl;
        float rs = 0.f;
#pragma unroll
        for (int nt = 0; nt < 4; nt++)
#pragma unroll
            for (int r = 0; r < 4; r++) {
                float e = __builtin_amdgcn_exp2f(fmaf(st[nt][r], Cl, -mC));
                st[nt][r] = e;
                rs += e;
            }
        rs += __shfl_xor(rs, 16, 64);
        rs += __shfl_xor(rs, 32, 64);
        li = li * alpha_v + rs;

        // P -> strip (truncation-pack via v_perm, b64 writes)
#pragma unroll
        for (int nt = 0; nt < 4; nt++) {
            uint2 pk;
            pk.x = __builtin_amdgcn_perm(fbits(st[nt][1]), fbits(st[nt][0]), 0x07060302u);
            pk.y = __builtin_amdgcn_perm(fbits(st[nt][3]), fbits(st[nt][2]), 0x07060302u);
            *(uint2*)&Ps[w][l16 * PSTR + nt * 16 + quad * 4] = pk;
        }
        // rescale O only when the running max moved (o rows are q=quad*4+r)
        if (need) {
            float a_o[4];
#pragma unroll
            for (int r = 0; r < 4; r++) a_o[r] = __shfl(alpha_v, quad * 4 + r, 64);
#pragma unroll
            for (int n2 = 0; n2 < 8; n2++)
#pragma unroll
                for (int r = 0; r < 4; r++) o[n2][r] *= a_o[r];
        }

        __syncthreads();                 // B2: V[kt] landed; all Ks reads done
        if (kt < qb) stageK(kt + 1);     // overwrite Ks; lands at next B1

        // O += P·V
#pragma unroll
        for (int ks2 = 0; ks2 < 2; ks2++) {
            short8 ap = *(const short8*)&Ps[w][l16 * PSTR + ks2 * 32 + quad * 8];
            __builtin_amdgcn_s_setprio(1);
#pragma unroll
            for (int n2 = 0; n2 < 8; n2++) {
                short8 bv = *(const short8*)&Vs[((n2 * 16 + l16) * 8 +
                                                ((ks2 * 4 + quad) ^ (l16 & 7))) * 8];
                o[n2] = __builtin_amdgcn_mfma_f32_16x16x32_bf16(ap, bv, o[n2], 0, 0, 0);
            }
            __builtin_amdgcn_s_setprio(0);
        }
    }

    // epilogue
    float linv[4];
#pragma unroll
    for (int r = 0; r < 4; r++) linv[r] = 1.0f / __shfl(li, quad * 4 + r, 64);
    u16* Ob2 = O + ((size_t)b * TT + qb * 64 + w * 16) * TDIM + h * HD;
#pragma unroll
    for (int n2 = 0; n2 < 8; n2++)
#pragma unroll
        for (int r = 0; r < 4; r++)
            Ob2[(size_t)(quad * 4 + r) * TDIM + n2 * 16 + l16] =
                f2b(o[n2][r] * linv[r]);
}

// ---------------------------------------------------------------------------
extern "C" void kernel_launch(void* const* d_in, const int* in_sizes, int n_in,
                              void* d_out, int out_size, void* d_ws, size_t ws_size,
                              hipStream_t stream) {
    const float* x  = (const float*)d_in[0];
    const float* fc = (const float*)d_in[1];
    const float* fs = (const float*)d_in[2];
    const float* wq = (const float*)d_in[3];
    const float* wk = (const float*)d_in[4];
    const float* wv = (const float*)d_in[5];
    const float* wo = (const float*)d_in[6];
    float* out = (float*)d_out;

    char* ws = (char*)d_ws;
    size_t off = 0;
    auto alloc = [&](size_t bytes) -> void* {
        void* p = ws + off;
        off += (bytes + 255) & ~(size_t)255;
        return p;
    };
    u16* xb  = (u16*)alloc((size_t)4096 * 2048 * 2);  // x in bf16
    u16* WT  = (u16*)alloc((size_t)3072 * 2048 * 2);  // [wqT|wkT|wvT] N x K bf16
    u16* woT = (u16*)alloc((size_t)2048 * 2048 * 2);
    u16* QKV = (u16*)alloc((size_t)4096 * 3072 * 2);  // [Q|K|V] fused bf16 (roped)
    u16* Vtb = (u16*)alloc((size_t)4096 * 512 * 2);   // V^T per (b,kv): [d][t]
    u16* Ob  = (u16*)alloc((size_t)4096 * 2048 * 2);  // attention output bf16

    dim3 blk(256);
    // fused x-convert (8192 blocks) + weight transposes (160 x 32 tiles)
    prep<<<dim3(8192 + 160 * 32), blk, 0, stream>>>(x, xb, wq, wk, wv, wo, WT, woT);
    // fused QKV projection with RoPE applied in the epilogue (Q|K cols only)
    gemm_bt<false, true><<<dim3(24, 32), blk, 0, stream>>>(
        xb, WT, QKV, 4096, 3072, 2048, fc, fs);
    transpose_v<<<dim3(32, 4, 8), blk, 0, stream>>>(QKV, Vtb);
    // 1024 blocks, 1D grid, globally longest-first (LPT); 3 blocks/CU
    attn<<<dim3(1024), blk, 0, stream>>>(QKV, Vtb, Ob);
    // out-projection: 512 blocks x 8 waves -> 16 waves/CU (was 4 waves, 8/CU)
    gemm_bt8w<true><<<dim3(16, 32), dim3(512), 0, stream>>>(
        Ob, woT, out, 4096, 2048, 2048);
}